// Round 2
// baseline (12105.291 us; speedup 1.0000x reference)
//
#include <hip/hip_runtime.h>
#include <math.h>

// Problem constants
#define BZ   32
#define TENC 1500
#define DD   512      // E == H == A == ATT_H == 512
#define VV   10000
#define LL   100
#define SS   101      // L+1 steps
#define G4   2048     // 4*H
#define KCZ  1024     // H + A

// d_out float offsets
#define OUT_LOGITS 0
#define OUT_ENCP   0                      // scratch overlay (dead before logits written)
#define OUT_PREG   24576000               // 32*1500*512
#define OUT_YSLP   32320000               // 32*101*10000
#define OUT_PRED   32323232
#define OUT_WS     32326464

__device__ inline float sigm(float x) { return 1.f / (1.f + __expf(-x)); }
__device__ inline float tanh_fast(float x) {
    x = fminf(15.f, fmaxf(-15.f, x));
    float e = __expf(2.f * x);
    return (e - 1.f) / (e + 1.f);
}

// ---------------------------------------------------------------------------
// Zero init: za slot 0 (32x1024), c_state (32x512), c_un (32x512), l_b, cnt
__global__ void zero_kernel(float* za0, float* cs, float* cu, float* lb, int* cnt) {
    int i = blockIdx.x * 256 + threadIdx.x;
    if (i < 32768) za0[i] = 0.f;
    else if (i < 49152) cs[i - 32768] = 0.f;
    else if (i < 65536) cu[i - 49152] = 0.f;
    else if (i < 65568) lb[i - 65536] = 0.f;
    else if (i < 65600) cnt[i - 65568] = 0;
}

// ---------------------------------------------------------------------------
// Tiled fp32 GEMM, 128x128 tile, 8x8 per thread.
// MODE 0: enc_proj = enc_pad[48000x512] @ W_enc[512x512]         (B normal)
// MODE 1: pre_g = emb[tok][3232x512] @ W_ih[:, :512]^T + biases  (B transposed, A gathered)
// MODE 2: logits = za(+32 rows)[3232x1024] @ W_out^T + b_out     (B transposed, scattered out rows)
template<int MODE>
__global__ __launch_bounds__(256) void gemm_tile(
    const float* __restrict__ Abase, const float* __restrict__ Bmat,
    const float* __restrict__ bias0, const float* __restrict__ bias1,
    const int* __restrict__ ys, float* __restrict__ Out,
    int M, int N, int K)
{
    __shared__ float As[16][132];
    __shared__ float Bs[16][132];
    const int tid = threadIdx.x;
    const int row0 = blockIdx.y * 128, n0 = blockIdx.x * 128;

    const int ar = tid >> 1, ah = tid & 1;
    int am = row0 + ar; if (am > M - 1) am = M - 1;
    const float* Arow;
    if (MODE == 0) {
        Arow = Abase + (size_t)am * 512;
    } else if (MODE == 1) {
        int t = am >> 5, b = am & 31;
        int tok = (t == 0) ? 1 : ys[b * LL + t - 1];
        Arow = Abase + (size_t)tok * 512;
    } else {
        Arow = Abase + (size_t)(am + 32) * 1024;
    }
    const int bk = tid >> 4, bg = tid & 15;          // MODE 0
    const int bn = tid >> 1, bh = tid & 1;           // MODE 1/2
    int bnn = n0 + bn; if (bnn > N - 1) bnn = N - 1;

    const int tx = tid & 15, ty = tid >> 4;
    const int rr = ty * 8, cc = tx * 8;
    float acc[8][8] = {{0.f}};

    for (int k0 = 0; k0 < K; k0 += 16) {
        float4 a0 = *(const float4*)(Arow + k0 + ah * 8);
        float4 a1 = *(const float4*)(Arow + k0 + ah * 8 + 4);
        As[ah*8+0][ar] = a0.x; As[ah*8+1][ar] = a0.y; As[ah*8+2][ar] = a0.z; As[ah*8+3][ar] = a0.w;
        As[ah*8+4][ar] = a1.x; As[ah*8+5][ar] = a1.y; As[ah*8+6][ar] = a1.z; As[ah*8+7][ar] = a1.w;
        if (MODE == 0) {
            const float* bp = Bmat + (size_t)(k0 + bk) * N + n0 + bg * 8;
            float4 b0 = *(const float4*)(bp);
            float4 b1 = *(const float4*)(bp + 4);
            *(float4*)&Bs[bk][bg * 8]     = b0;
            *(float4*)&Bs[bk][bg * 8 + 4] = b1;
        } else {
            const float* bp = Bmat + (size_t)bnn * 1024 + k0 + bh * 8;
            float4 b0 = *(const float4*)(bp);
            float4 b1 = *(const float4*)(bp + 4);
            Bs[bh*8+0][bn] = b0.x; Bs[bh*8+1][bn] = b0.y; Bs[bh*8+2][bn] = b0.z; Bs[bh*8+3][bn] = b0.w;
            Bs[bh*8+4][bn] = b1.x; Bs[bh*8+5][bn] = b1.y; Bs[bh*8+6][bn] = b1.z; Bs[bh*8+7][bn] = b1.w;
        }
        __syncthreads();
        #pragma unroll
        for (int kk = 0; kk < 16; ++kk) {
            float4 A0 = *(const float4*)&As[kk][rr];
            float4 A1 = *(const float4*)&As[kk][rr + 4];
            float4 B0 = *(const float4*)&Bs[kk][cc];
            float4 B1 = *(const float4*)&Bs[kk][cc + 4];
            float av[8] = {A0.x, A0.y, A0.z, A0.w, A1.x, A1.y, A1.z, A1.w};
            float bv[8] = {B0.x, B0.y, B0.z, B0.w, B1.x, B1.y, B1.z, B1.w};
            #pragma unroll
            for (int i = 0; i < 8; ++i)
                #pragma unroll
                for (int j = 0; j < 8; ++j)
                    acc[i][j] += av[i] * bv[j];
        }
        __syncthreads();
    }
    #pragma unroll
    for (int i = 0; i < 8; ++i) {
        int m = row0 + rr + i;
        if (m >= M) continue;
        size_t orow;
        if (MODE == 2) { int t = m >> 5, b = m & 31; orow = ((size_t)b * SS + t) * (size_t)N; }
        else orow = (size_t)m * N;
        #pragma unroll
        for (int j = 0; j < 8; ++j) {
            int n = n0 + cc + j;
            if (n < N) {
                float v = acc[i][j];
                if (MODE == 1) v += bias0[n] + bias1[n];
                if (MODE == 2) v += bias0[n];
                Out[orow + n] = v;
            }
        }
    }
}

// ---------------------------------------------------------------------------
// Fused gates + LSTM elementwise. One block per h (512 blocks).
// Thread: b = tid&31, u = tid>>5; g = u&3 (gate), half = u>>2 (K-half).
__global__ __launch_bounds__(256) void k_cell(
    const float* __restrict__ za_t, const float* __restrict__ pre_g_t,
    const float* __restrict__ W_ih, const float* __restrict__ W_hh,
    float* __restrict__ c_state, float* __restrict__ za_next)
{
    __shared__ float sdot[8][33];
    __shared__ float sg[4][33];
    const int tid = threadIdx.x;
    const int h = blockIdx.x;
    const int b = tid & 31, u = tid >> 5, g = u & 3, half = u >> 2;
    const int r = g * 512 + h;
    const float* x = za_t + b * KCZ + half * 512;
    const float* w = (half == 0) ? (W_hh + (size_t)r * 512)
                                 : (W_ih + (size_t)r * 1024 + 512);
    float a0 = 0.f, a1 = 0.f;
    #pragma unroll 8
    for (int k = 0; k < 512; k += 8) {
        float4 x0 = *(const float4*)(x + k);
        float4 x1 = *(const float4*)(x + k + 4);
        float4 w0 = *(const float4*)(w + k);
        float4 w1 = *(const float4*)(w + k + 4);
        a0 += x0.x*w0.x + x0.y*w0.y + x0.z*w0.z + x0.w*w0.w;
        a1 += x1.x*w1.x + x1.y*w1.y + x1.z*w1.z + x1.w*w1.w;
    }
    sdot[u][b] = a0 + a1;
    __syncthreads();
    if (u < 4)
        sg[u][b] = sdot[u][b] + sdot[u + 4][b] + pre_g_t[b * G4 + u * 512 + h];
    __syncthreads();
    if (tid < 32) {
        float ig = sigm(sg[0][tid]);
        float fg = sigm(sg[1][tid]);
        float gg = tanhf(sg[2][tid]);
        float og = sigm(sg[3][tid]);
        float c = fg * c_state[tid * 512 + h] + ig * gg;
        c_state[tid * 512 + h] = c;
        za_next[tid * KCZ + h] = og * tanhf(c);
    }
}

// ---------------------------------------------------------------------------
// q = z @ W_dec. grid (4 j-slices, 32 b), 128 threads; z loads are b-uniform
// (scalarized), W_dec slice 256KB/block stream.
__global__ __launch_bounds__(128) void k_qproj(const float* __restrict__ za_next,
                                               const float* __restrict__ W_dec,
                                               float* __restrict__ q)
{
    const int j = blockIdx.x * 128 + threadIdx.x;
    const int b = blockIdx.y;
    const float* z = za_next + b * KCZ;
    float a0 = 0.f, a1 = 0.f;
    #pragma unroll 4
    for (int h = 0; h < 512; h += 2) {
        a0 += z[h]     * W_dec[(size_t)h * 512 + j];
        a1 += z[h + 1] * W_dec[(size_t)(h + 1) * 512 + j];
    }
    q[b * 512 + j] = a0 + a1;
}

// ---------------------------------------------------------------------------
// Fused attention: score -> p=exp(e-10) -> unnormalized context, plus
// last-arrival finalize (c normalization into za_next). 512 thr = 8 waves.
__global__ __launch_bounds__(512) void k_att(
    const float* __restrict__ enc_proj, const float* __restrict__ enc_pad,
    const float* __restrict__ q, const float* __restrict__ v_att,
    const int* __restrict__ enc_len,
    float* __restrict__ c_un, float* __restrict__ l_b, int* __restrict__ cnt,
    float* __restrict__ za_next, float* __restrict__ w_all,
    float* __restrict__ l_all, int t)
{
    __shared__ float q_s[512], v_s[512];
    __shared__ float accs[8][512];
    __shared__ float lsum_s[8];
    __shared__ int sflag;
    const int b = blockIdx.y, tc = blockIdx.x, tid = threadIdx.x;
    q_s[tid] = q[b * 512 + tid];
    v_s[tid] = v_att[tid];
    __syncthreads();
    const int len = enc_len[b];
    const int base = tc * 128;
    int tlim = base + 128;
    if (tlim > TENC) tlim = TENC;
    if (tlim > len) tlim = len;
    const int wave = tid >> 6, lane = tid & 63;
    float a[8] = {0.f, 0.f, 0.f, 0.f, 0.f, 0.f, 0.f, 0.f};
    float lacc = 0.f;
    float qv[8], vv[8];
    #pragma unroll
    for (int j = 0; j < 8; ++j) { qv[j] = q_s[lane * 8 + j]; vv[j] = v_s[lane * 8 + j]; }
    float* wrow = w_all + ((size_t)b * SS + t) * TENC;

    #pragma unroll 2
    for (int tp = base + wave; tp < tlim; tp += 8) {
        const float* ep = enc_proj + ((size_t)b * TENC + tp) * 512 + lane * 8;
        float4 e0 = *(const float4*)(ep);
        float4 e1 = *(const float4*)(ep + 4);
        const float* xp = enc_pad + ((size_t)b * TENC + tp) * 512 + lane * 8;
        float4 x0 = *(const float4*)(xp);
        float4 x1 = *(const float4*)(xp + 4);
        float s = tanh_fast(e0.x + qv[0]) * vv[0] + tanh_fast(e0.y + qv[1]) * vv[1]
                + tanh_fast(e0.z + qv[2]) * vv[2] + tanh_fast(e0.w + qv[3]) * vv[3]
                + tanh_fast(e1.x + qv[4]) * vv[4] + tanh_fast(e1.y + qv[5]) * vv[5]
                + tanh_fast(e1.z + qv[6]) * vv[6] + tanh_fast(e1.w + qv[7]) * vv[7];
        #pragma unroll
        for (int off = 32; off > 0; off >>= 1) s += __shfl_xor(s, off);
        float p = __expf(s - 10.f);
        if (lane == 0) wrow[tp] = p;                 // unnormalized; k_wnorm fixes
        lacc += p;
        a[0] += p * x0.x; a[1] += p * x0.y; a[2] += p * x0.z; a[3] += p * x0.w;
        a[4] += p * x1.x; a[5] += p * x1.y; a[6] += p * x1.z; a[7] += p * x1.w;
    }
    #pragma unroll
    for (int j = 0; j < 8; ++j) accs[wave][lane * 8 + j] = a[j];
    if (lane == 0) lsum_s[wave] = lacc;
    __syncthreads();
    if (tlim > base) {
        float s = 0.f;
        #pragma unroll
        for (int w8 = 0; w8 < 8; ++w8) s += accs[w8][tid];
        atomicAdd(&c_un[b * 512 + tid], s);
        if (tid == 0) {
            float ls = 0.f;
            #pragma unroll
            for (int w8 = 0; w8 < 8; ++w8) ls += lsum_s[w8];
            atomicAdd(&l_b[b], ls);
        }
    }
    __syncthreads();   // barrier drains each wave's vmem -> atomics complete
    if (tid == 0) {
        __threadfence();
        int old = atomicAdd(&cnt[b], 1);
        sflag = (old == 11);
    }
    __syncthreads();
    if (sflag) {
        // all 12 chunk-blocks for this b are done; their adds went through the
        // coherent point (atomics). Read via agent-scope atomic loads.
        float l = __hip_atomic_load(&l_b[b], __ATOMIC_RELAXED, __HIP_MEMORY_SCOPE_AGENT);
        float linv = 1.f / l;
        float cu = __hip_atomic_load(&c_un[b * 512 + tid], __ATOMIC_RELAXED, __HIP_MEMORY_SCOPE_AGENT);
        za_next[b * KCZ + 512 + tid] = cu * linv;
        __hip_atomic_store(&c_un[b * 512 + tid], 0.f, __ATOMIC_RELAXED, __HIP_MEMORY_SCOPE_AGENT);
        if (tid == 0) {
            l_all[t * 32 + b] = l;
            __hip_atomic_store(&l_b[b], 0.f, __ATOMIC_RELAXED, __HIP_MEMORY_SCOPE_AGENT);
            __hip_atomic_store(&cnt[b], 0, __ATOMIC_RELAXED, __HIP_MEMORY_SCOPE_AGENT);
        }
    }
}

// ---------------------------------------------------------------------------
// Normalize + mask all attention rows at the end. grid = 32*101 rows.
__global__ void k_wnorm(const float* __restrict__ l_all, const int* __restrict__ enc_len,
                        float* __restrict__ w_all)
{
    const int bid = blockIdx.x;            // = b*SS + t
    const int b = bid / SS, t = bid % SS;
    const int len = enc_len[b];
    const float linv = 1.f / l_all[t * 32 + b];
    float* row = w_all + (size_t)bid * TENC;
    for (int tp = threadIdx.x; tp < TENC; tp += 256)
        row[tp] = (tp < len) ? row[tp] * linv : 0.f;
}

// ---------------------------------------------------------------------------
// Per-row log-softmax stats: max, argmax(first), logsumexp -> ys_lp, pred
__global__ __launch_bounds__(256) void k_logsm(const float* __restrict__ logits,
                                               const int* __restrict__ ys,
                                               float* __restrict__ ys_lp,
                                               float* __restrict__ pred)
{
    __shared__ float sval[256];
    __shared__ int   sidx[256];
    __shared__ float ssum[256];
    const int bid = blockIdx.x, tid = threadIdx.x;
    const float* row = logits + (size_t)bid * VV;
    float vmax = -3.4e38f; int imax = 0;
    for (int v4 = tid; v4 < VV / 4; v4 += 256) {
        float4 x = *(const float4*)(row + v4 * 4);
        int basei = v4 * 4;
        if (x.x > vmax) { vmax = x.x; imax = basei; }
        if (x.y > vmax) { vmax = x.y; imax = basei + 1; }
        if (x.z > vmax) { vmax = x.z; imax = basei + 2; }
        if (x.w > vmax) { vmax = x.w; imax = basei + 3; }
    }
    sval[tid] = vmax; sidx[tid] = imax;
    __syncthreads();
    for (int s = 128; s > 0; s >>= 1) {
        if (tid < s) {
            float v2 = sval[tid + s]; int i2 = sidx[tid + s];
            if (v2 > sval[tid] || (v2 == sval[tid] && i2 < sidx[tid])) { sval[tid] = v2; sidx[tid] = i2; }
        }
        __syncthreads();
    }
    const float gmax = sval[0];
    float lsum = 0.f;
    for (int v4 = tid; v4 < VV / 4; v4 += 256) {
        float4 x = *(const float4*)(row + v4 * 4);
        lsum += __expf(x.x - gmax) + __expf(x.y - gmax) + __expf(x.z - gmax) + __expf(x.w - gmax);
    }
    ssum[tid] = lsum;
    __syncthreads();
    for (int s = 128; s > 0; s >>= 1) {
        if (tid < s) ssum[tid] += ssum[tid + s];
        __syncthreads();
    }
    if (tid == 0) {
        int b = bid / SS, t = bid % SS;
        int tok = (t < LL) ? ys[b * LL + t] : 2;   // EOS = 2
        ys_lp[bid] = row[tok] - gmax - logf(ssum[0]);
        pred[bid]  = (float)sidx[0];
    }
}

// ---------------------------------------------------------------------------
extern "C" void kernel_launch(void* const* d_in, const int* in_sizes, int n_in,
                              void* d_out, int out_size, void* d_ws, size_t ws_size,
                              hipStream_t stream)
{
    const float* enc_pad = (const float*)d_in[0];
    const int*   enc_len = (const int*)d_in[1];
    const int*   ys      = (const int*)d_in[2];
    const float* emb     = (const float*)d_in[3];
    const float* W_ih    = (const float*)d_in[4];
    const float* W_hh    = (const float*)d_in[5];
    const float* b_ih    = (const float*)d_in[6];
    const float* b_hh    = (const float*)d_in[7];
    const float* W_enc   = (const float*)d_in[8];
    const float* W_dec   = (const float*)d_in[9];
    const float* v_att   = (const float*)d_in[10];
    const float* W_out   = (const float*)d_in[11];
    const float* b_out   = (const float*)d_in[12];

    float* out = (float*)d_out;
    float* enc_proj = out + OUT_ENCP;
    float* pre_g    = out + OUT_PREG;
    float* logits   = out + OUT_LOGITS;
    float* ys_lp    = out + OUT_YSLP;
    float* predo    = out + OUT_PRED;
    float* wsatt    = out + OUT_WS;

    float* ws = (float*)d_ws;
    float* za      = ws;                    // 102*32*1024 = 3342336
    float* c_state = za + 3342336;          // 16384
    float* q       = c_state + 16384;       // 16384
    float* c_un    = q + 16384;             // 16384
    float* l_b     = c_un + 16384;          // 32
    float* l_all   = l_b + 32;              // 3232
    int*   cnt     = (int*)(l_all + 3232);  // 32

    // Prologue
    zero_kernel<<<257, 256, 0, stream>>>(za, c_state, c_un, l_b, cnt);
    gemm_tile<0><<<dim3(4, 375), 256, 0, stream>>>(enc_pad, W_enc, nullptr, nullptr, nullptr,
                                                   enc_proj, BZ * TENC, 512, 512);
    gemm_tile<1><<<dim3(16, 26), 256, 0, stream>>>(emb, W_ih, b_ih, b_hh, ys,
                                                   pre_g, BZ * SS, G4, 512);

    // Sequential decode: 3 kernels per step
    for (int t = 0; t < SS; ++t) {
        float* za_t    = za + (size_t)t * (BZ * KCZ);
        float* za_next = za + (size_t)(t + 1) * (BZ * KCZ);
        k_cell<<<512, 256, 0, stream>>>(za_t, pre_g + (size_t)t * (BZ * G4),
                                        W_ih, W_hh, c_state, za_next);
        k_qproj<<<dim3(4, 32), 128, 0, stream>>>(za_next, W_dec, q);
        k_att<<<dim3(12, 32), 512, 0, stream>>>(enc_proj, enc_pad, q, v_att, enc_len,
                                                c_un, l_b, cnt, za_next, wsatt, l_all, t);
    }

    // Epilogue
    gemm_tile<2><<<dim3(79, 26), 256, 0, stream>>>(za, W_out, b_out, nullptr, nullptr,
                                                   logits, BZ * SS, VV, 1024);
    k_logsm<<<BZ * SS, 256, 0, stream>>>(logits, ys, ys_lp, predo);
    k_wnorm<<<BZ * SS, 256, 0, stream>>>(l_all, enc_len, wsatt);
}